// Round 4
// baseline (281.338 us; speedup 1.0000x reference)
//
#include <hip/hip_runtime.h>
#include <math.h>

#define IM 128
#define BZ 32

typedef float v4f __attribute__((ext_vector_type(4)));

// R4 = R3 structure + NONTEMPORAL output stores (single-variable experiment).
//
// Mechanism under test: out (270 MB) is write-once and exceeds the 256 MB L3,
// so plain stores write-allocate through L2/L3 and thrash both every timed
// iteration, evicting the x rows the DFT phase re-reads 129x from L2.
// NT stores stream writes past the caches; x stays resident. Session-0
// evidence: plain-store variant 276.4 us vs 265.6 us best with NT stores.
//
// One block per (b, v): grid = 32 * 129 = 4128 blocks, 256 threads, 1 KB LDS.
//   DFT:  thread (h = tid>>1, part = tid&1) reads x[b,h,part*64..+63] from
//         global (L2-hit after first touch; XCD-chunked swizzle keeps all 129
//         v-blocks of a batch on one XCD), in-register phasor recurrence,
//         shfl-reduce, t stashed in 1 KB LDS.
//   emit: out[b,v,h,w] = tre[h] cos(A v w) - tim[h] sin(A v w); exact
//         loop-invariant twiddles (k = v*w mod 128); 1 KB/wave sequential
//         NT stores over the block's contiguous 64 KB tile.
//   v==128 blocks: contiguous passthrough copy, NT on both sides.

__global__ __launch_bounds__(256) void kspace_fused(const float* __restrict__ in,
                                                    float* __restrict__ out) {
    const int g   = blockIdx.x;                        // 0..4127
    const int lin = (g & 7) * 516 + (g >> 3);          // XCD-chunked (4128%8==0)
    const int b   = (int)((unsigned)lin / 129u);
    const int v   = lin - b * 129;
    const int tid = threadIdx.x;                       // 0..255

    float* tile = out + ((size_t)b * 129 + v) * (IM * IM);

    if (v == IM) {
        // passthrough: out[b,128,:,:] = input[b,1,:,:]  (contiguous 64 KB)
        const v4f* src = (const v4f*)(in + ((size_t)b * 2 + 1) * IM * IM);
        v4f*       dst = (v4f*)tile;
        #pragma unroll
        for (int i = 0; i < 16; ++i) {
            const v4f t = __builtin_nontemporal_load(src + i * 256 + tid);
            __builtin_nontemporal_store(t, dst + i * 256 + tid);
        }
        return;
    }

    const float A = 6.28318530717958647692f / (float)IM;   // 2*pi/128
    __shared__ float tre[IM], tim[IM];

    // ---- DFT: t[v,h], two 64-term halves per h ----
    {
        const int h    = tid >> 1;
        const int part = tid & 1;
        const int wb   = part << 6;                    // 0 or 64
        const float* xr = in + (size_t)b * 2 * IM * IM + (size_t)h * IM + wb;

        float pc, ps;
        { int k = (v * wb) & (IM - 1); sincosf(A * (float)k, &ps, &pc); ps = -ps; }
        float rc, rs;
        sincosf(A * (float)v, &rs, &rc); rs = -rs;     // step e^{-2pi i v/128}

        float sre = 0.0f, sim = 0.0f;
        #pragma unroll 4
        for (int i = 0; i < 16; ++i) {
            const v4f xv = *(const v4f*)(xr + 4 * i);  // plain load: keep in L2
            float n;
            sre = fmaf(xv.x, pc, sre); sim = fmaf(xv.x, ps, sim);
            n = pc * rc - ps * rs; ps = fmaf(ps, rc, pc * rs); pc = n;
            sre = fmaf(xv.y, pc, sre); sim = fmaf(xv.y, ps, sim);
            n = pc * rc - ps * rs; ps = fmaf(ps, rc, pc * rs); pc = n;
            sre = fmaf(xv.z, pc, sre); sim = fmaf(xv.z, ps, sim);
            n = pc * rc - ps * rs; ps = fmaf(ps, rc, pc * rs); pc = n;
            sre = fmaf(xv.w, pc, sre); sim = fmaf(xv.w, ps, sim);
            n = pc * rc - ps * rs; ps = fmaf(ps, rc, pc * rs); pc = n;
        }
        sre += __shfl_xor(sre, 1);
        sim += __shfl_xor(sim, 1);
        if (part == 0) {
            tre[h] = sre * (1.0f / IM);                // even lanes, consecutive
            tim[h] = sim * (1.0f / IM);                //   addresses: conflict-free
        }
    }
    __syncthreads();

    // ---- emit: contiguous 64 KB tile, loop-invariant exact twiddles ----
    const int w0   = (tid & 31) * 4;                   // 0,4,...,124
    const int hsub = tid >> 5;                         // 0..7

    float cw[4], sw[4];
    #pragma unroll
    for (int j = 0; j < 4; ++j) {
        const int k = (v * (w0 + j)) & (IM - 1);       // exact k = v*w mod 128
        sincosf(A * (float)k, &sw[j], &cw[j]);
    }

    #pragma unroll
    for (int i = 0; i < 16; ++i) {
        const int h = i * 8 + hsub;
        const float re = tre[h];                       // 2-addr broadcast reads
        const float im = tim[h];
        v4f r;
        r.x = re * cw[0] - im * sw[0];
        r.y = re * cw[1] - im * sw[1];
        r.z = re * cw[2] - im * sw[2];
        r.w = re * cw[3] - im * sw[3];
        __builtin_nontemporal_store(r, (v4f*)(tile + (size_t)h * IM + w0));
    }
}

extern "C" void kernel_launch(void* const* d_in, const int* in_sizes, int n_in,
                              void* d_out, int out_size, void* d_ws, size_t ws_size,
                              hipStream_t stream) {
    const float* in = (const float*)d_in[0];   // (32, 2, 128, 128) fp32; mask unused
    float* out = (float*)d_out;                // (32, 129, 128, 128) fp32
    kspace_fused<<<dim3(BZ * 129), dim3(256), 0, stream>>>(in, out);
}

// Round 6
// 271.344 us; speedup vs baseline: 1.0368x; 1.0368x over previous
//
#include <hip/hip_runtime.h>
#include <math.h>

#define IM 128
#define BZ 32

typedef float v4f __attribute__((ext_vector_type(4)));

// R6 = resubmit of R5 (bench infra failed; kernel itself is the best-verified
// variant with a two-run pedigree: 265.6 us prior session, 276.4 us this one).
//
// Session synthesis: five structural variants (scattered stores / 2-pass /
// fat-block contiguous @4 waves/CU / slim-block contiguous @32 waves/CU /
// nontemporal stores) all tie within the +/-11 us same-code remeasurement
// band. Rest-time is insensitive to occupancy (8x) and store pattern
// (scattered vs sequential) => the kernel portion is at its ~43 us write
// floor (274 MB compulsory traffic at the fill-demonstrated 6.4 TB/s);
// the remainder of dur_us is harness fill (~170 us) + fixed per-iteration
// overhead (~55 us) that no kernel change moves.
//
// One block per (b, h) row of x = input[:,0,:,:].
//   t[v]         = sum_w x[w] * e^{-2pi i v w/128}   (ifft(fft2) = row DFT)
//   sep[b,v,h,w] = Re( t[v] * e^{+2pi i v w/128} ) / 128
// out layout: (B, 129, 128, 128); channel 128 = input[:,1,:,:].
// Twiddles via in-register phasor recurrences (no LDS gathers).
__global__ __launch_bounds__(256) void kspace_kernel(const float* __restrict__ in,
                                                     float* __restrict__ out) {
    const int row = blockIdx.x;        // 0 .. BZ*IM-1
    const int b   = row >> 7;
    const int h   = row & (IM - 1);
    const int tid = threadIdx.x;       // 0 .. 255

    const float A = 6.28318530717958647692f / (float)IM;   // 2*pi/128

    __shared__ float xr[IM];
    __shared__ float tre[IM];
    __shared__ float tim[IM];

    // ---- stage x row ----
    const float* xrow = in + (((size_t)b * 2 + 0) * IM + h) * IM;
    if (tid < IM) xr[tid] = xrow[tid];
    __syncthreads();

    // ---- 128-point DFT: v = tid/2, each half sums 64 terms, phasor recurrence ----
    {
        const int v     = tid >> 1;
        const int part  = tid & 1;
        const int wbase = part << 6;                       // 0 or 64

        // phasor p = e^{-2pi i v (wbase+i)/128}, step r = e^{-2pi i v/128}
        float pc, ps;
        { int k = (v * wbase) & (IM - 1); sincosf(A * (float)k, &ps, &pc); ps = -ps; }
        float rc, rs;
        sincosf(A * (float)v, &rs, &rc); rs = -rs;

        float sre = 0.0f, sim = 0.0f;
        #pragma unroll 8
        for (int i = 0; i < 64; ++i) {
            const float xv = xr[wbase + i];                // 2 addrs/wave: conflict-free
            sre = fmaf(xv, pc, sre);
            sim = fmaf(xv, ps, sim);
            const float npc = pc * rc - ps * rs;
            ps = fmaf(ps, rc, pc * rs);
            pc = npc;
        }
        sre += __shfl_xor(sre, 1);
        sim += __shfl_xor(sim, 1);
        if (part == 0) {
            tre[v] = sre * (1.0f / IM);
            tim[v] = sim * (1.0f / IM);
        }
    }
    __syncthreads();

    // ---- emit: thread (vsub = tid>>5, w0 = (tid&31)*4), 16 iters over v = it*8+vsub ----
    float* outb = out + (size_t)b * 129 * IM * IM + (size_t)h * IM;
    const int vsub = tid >> 5;            // 0..7
    const int w0   = (tid & 31) * 4;      // 0,4,...,124

    // P = e^{2pi i v w0/128} (v starts at vsub), per-iter P *= W, W = e^{2pi i 8 w0/128}
    // R = e^{2pi i v/128},                       per-iter R *= S, S = e^{i pi/8}
    float pc, ps;
    { int k = (vsub * w0) & (IM - 1); sincosf(A * (float)k, &ps, &pc); }
    float rc, rs;
    sincosf(A * (float)vsub, &rs, &rc);
    float wc, ws;
    { int k = (8 * w0) & (IM - 1); sincosf(A * (float)k, &ws, &wc); }
    const float sc = 0.92387953251128675613f;   // cos(pi/8)
    const float ss = 0.38268343236508977173f;   // sin(pi/8)

    #pragma unroll
    for (int it = 0; it < 16; ++it) {
        const int v = it * 8 + vsub;
        const float re = tre[v];          // 2 addresses per wave: conflict-free
        const float im = tim[v];

        v4f r;
        float c = pc, s = ps;
        r.x = re * c - im * s;
        float nc = c * rc - s * rs; s = fmaf(s, rc, c * rs); c = nc;
        r.y = re * c - im * s;
        nc = c * rc - s * rs; s = fmaf(s, rc, c * rs); c = nc;
        r.z = re * c - im * s;
        nc = c * rc - s * rs; s = fmaf(s, rc, c * rs); c = nc;
        r.w = re * c - im * s;
        *(v4f*)(outb + (size_t)v * IM * IM + w0) = r;

        // advance recurrences for next v = v + 8
        nc = pc * wc - ps * ws; ps = fmaf(ps, wc, pc * ws); pc = nc;
        nc = rc * sc - rs * ss; rs = fmaf(rs, sc, rc * ss); rc = nc;
    }

    // ---- passthrough: out[b, 128, h, :] = input[b, 1, h, :] ----
    if (tid < 32) {
        const v4f* src = (const v4f*)(in + (((size_t)b * 2 + 1) * IM + h) * IM);
        v4f*       dst = (v4f*)(out + (((size_t)b * 129 + 128) * IM + h) * IM);
        dst[tid] = src[tid];
    }
}

extern "C" void kernel_launch(void* const* d_in, const int* in_sizes, int n_in,
                              void* d_out, int out_size, void* d_ws, size_t ws_size,
                              hipStream_t stream) {
    const float* in = (const float*)d_in[0];   // (32, 2, 128, 128) fp32; mask unused
    float* out = (float*)d_out;                // (32, 129, 128, 128) fp32
    kspace_kernel<<<dim3(BZ * IM), dim3(256), 0, stream>>>(in, out);
}